// Round 5
// baseline (381.252 us; speedup 1.0000x reference)
//
#include <hip/hip_runtime.h>
#include <hip/hip_bf16.h>
#include <hip/hip_fp16.h>
#include <math.h>

// Problem constants: B=32, L=128, D=6, T=63, V=50000, E=C=128, H=256
#define NV 50000
#define NC 128
#define NH 256
#define NB 32
#define NL 128
#define NT 63
#define G3 768   // 3*H

typedef _Float16 half2_t __attribute__((ext_vector_type(2)));

__device__ __forceinline__ float sigmoidf_(float x) { return 1.0f / (1.0f + expf(-x)); }

__device__ __forceinline__ float fdot2_(unsigned int a, unsigned int b, float c) {
#if __has_builtin(__builtin_amdgcn_fdot2)
  return __builtin_amdgcn_fdot2(__builtin_bit_cast(half2_t, a),
                                __builtin_bit_cast(half2_t, b), c, false);
#else
  half2_t ah = __builtin_bit_cast(half2_t, a);
  half2_t bh = __builtin_bit_cast(half2_t, b);
  return fmaf((float)ah[0], (float)bh[0], fmaf((float)ah[1], (float)bh[1], c));
#endif
}

// ---------------------------------------------------------------------------
// C[m][n] = sum_k A[m][k]*B[n][k] (+bias), K=128. B staged in two k-halves.
// ---------------------------------------------------------------------------
__global__ __launch_bounds__(256) void gemm_bt_k128(
    const float* __restrict__ A, const float* __restrict__ Bm,
    const float* __restrict__ bias, float* __restrict__ Cm,
    int M, int N) {
  __shared__ __align__(16) float As[64 * 129];
  __shared__ __align__(16) float BsT[64 * 132];  // [kk][n], one k-half
  const int m0 = blockIdx.x * 64;
  const int n0 = blockIdx.y * 128;
  const int tid = threadIdx.x;

#pragma unroll
  for (int i = 0; i < 32; ++i) {
    int e = tid + i * 256;
    int r = e >> 7, k = e & 127;
    int m = m0 + r;
    As[r * 129 + k] = (m < M) ? A[(size_t)m * 128 + k] : 0.0f;
  }

  const int tn = tid & 15;
  const int tm = tid >> 4;
  const int ml = tm * 4, nl = tn * 8;

  float acc[4][8];
#pragma unroll
  for (int i = 0; i < 4; ++i)
#pragma unroll
    for (int j = 0; j < 8; ++j) acc[i][j] = 0.0f;

#pragma unroll
  for (int h = 0; h < 2; ++h) {
    if (h) __syncthreads();
#pragma unroll
    for (int i = 0; i < 32; ++i) {
      int e = tid + i * 256;
      int n = e >> 6, kk = e & 63;
      BsT[kk * 132 + n] = Bm[(size_t)(n0 + n) * 128 + h * 64 + kk];
    }
    __syncthreads();
#pragma unroll 4
    for (int kk = 0; kk < 64; ++kk) {
      const int k = h * 64 + kk;
      float a0 = As[(ml + 0) * 129 + k];
      float a1 = As[(ml + 1) * 129 + k];
      float a2 = As[(ml + 2) * 129 + k];
      float a3 = As[(ml + 3) * 129 + k];
      float4 b0 = *(const float4*)&BsT[kk * 132 + nl];
      float4 b1 = *(const float4*)&BsT[kk * 132 + nl + 4];
      const float bv[8] = {b0.x, b0.y, b0.z, b0.w, b1.x, b1.y, b1.z, b1.w};
#pragma unroll
      for (int j = 0; j < 8; ++j) {
        acc[0][j] = fmaf(a0, bv[j], acc[0][j]);
        acc[1][j] = fmaf(a1, bv[j], acc[1][j]);
        acc[2][j] = fmaf(a2, bv[j], acc[2][j]);
        acc[3][j] = fmaf(a3, bv[j], acc[3][j]);
      }
    }
  }

  float bv[8];
#pragma unroll
  for (int j = 0; j < 8; ++j) bv[j] = bias ? bias[n0 + nl + j] : 0.0f;

#pragma unroll
  for (int i = 0; i < 4; ++i) {
    int m = m0 + ml + i;
    if (m < M) {
      float* crow = &Cm[(size_t)m * N + n0 + nl];
#pragma unroll
      for (int j = 0; j < 8; ++j) crow[j] = acc[i][j] + bv[j];
    }
  }
}

// ---------------------------------------------------------------------------
// Dual GEMM: blockIdx.z picks f/b weight+bias+output.
// ---------------------------------------------------------------------------
__global__ __launch_bounds__(256) void gemm_bt_k128_dual(
    const float* __restrict__ A,
    const float* __restrict__ B0, const float* __restrict__ B1,
    const float* __restrict__ bias0, const float* __restrict__ bias1,
    float* __restrict__ C0, float* __restrict__ C1, int M, int N) {
  const float* __restrict__ Bm = blockIdx.z ? B1 : B0;
  const float* __restrict__ bias = blockIdx.z ? bias1 : bias0;
  float* __restrict__ Cm = blockIdx.z ? C1 : C0;

  __shared__ __align__(16) float As[64 * 129];
  __shared__ __align__(16) float BsT[64 * 132];
  const int m0 = blockIdx.x * 64;
  const int n0 = blockIdx.y * 128;
  const int tid = threadIdx.x;

#pragma unroll
  for (int i = 0; i < 32; ++i) {
    int e = tid + i * 256;
    int r = e >> 7, k = e & 127;
    int m = m0 + r;
    As[r * 129 + k] = (m < M) ? A[(size_t)m * 128 + k] : 0.0f;
  }

  const int tn = tid & 15;
  const int tm = tid >> 4;
  const int ml = tm * 4, nl = tn * 8;

  float acc[4][8];
#pragma unroll
  for (int i = 0; i < 4; ++i)
#pragma unroll
    for (int j = 0; j < 8; ++j) acc[i][j] = 0.0f;

#pragma unroll
  for (int h = 0; h < 2; ++h) {
    if (h) __syncthreads();
#pragma unroll
    for (int i = 0; i < 32; ++i) {
      int e = tid + i * 256;
      int n = e >> 6, kk = e & 63;
      BsT[kk * 132 + n] = Bm[(size_t)(n0 + n) * 128 + h * 64 + kk];
    }
    __syncthreads();
#pragma unroll 4
    for (int kk = 0; kk < 64; ++kk) {
      const int k = h * 64 + kk;
      float a0 = As[(ml + 0) * 129 + k];
      float a1 = As[(ml + 1) * 129 + k];
      float a2 = As[(ml + 2) * 129 + k];
      float a3 = As[(ml + 3) * 129 + k];
      float4 b0 = *(const float4*)&BsT[kk * 132 + nl];
      float4 b1 = *(const float4*)&BsT[kk * 132 + nl + 4];
      const float bv[8] = {b0.x, b0.y, b0.z, b0.w, b1.x, b1.y, b1.z, b1.w};
#pragma unroll
      for (int j = 0; j < 8; ++j) {
        acc[0][j] = fmaf(a0, bv[j], acc[0][j]);
        acc[1][j] = fmaf(a1, bv[j], acc[1][j]);
        acc[2][j] = fmaf(a2, bv[j], acc[2][j]);
        acc[3][j] = fmaf(a3, bv[j], acc[3][j]);
      }
    }
  }

  float bv[8];
#pragma unroll
  for (int j = 0; j < 8; ++j) bv[j] = bias[n0 + nl + j];

#pragma unroll
  for (int i = 0; i < 4; ++i) {
    int m = m0 + ml + i;
    if (m < M) {
      float* crow = &Cm[(size_t)m * N + n0 + nl];
#pragma unroll
      for (int j = 0; j < 8; ++j) crow[j] = acc[i][j] + bv[j];
    }
  }
}

// ---------------------------------------------------------------------------
// Tree encode: per (b,l), heap-sum P[tok], + cnt*bc, max, relu.
// ---------------------------------------------------------------------------
__global__ __launch_bounds__(128) void tree_encode(
    const int* __restrict__ tokens, const float* __restrict__ P,
    const float* __restrict__ bc, float* __restrict__ enc) {
  __shared__ int toks[NT];
  const int blk = blockIdx.x;
  const int c = threadIdx.x;
  if (c < NT) toks[c] = tokens[(size_t)blk * NT + c];
  __syncthreads();

  float s[NT];
#pragma unroll
  for (int i = 0; i < NT; ++i) s[i] = P[(size_t)toks[i] * NC + c];
#pragma unroll
  for (int i = 30; i >= 0; --i) s[i] += s[2 * i + 1] + s[2 * i + 2];

  const float bcv = bc[c];
  float m = -1e30f;
#pragma unroll
  for (int i = 0; i < NT; ++i) {
    const float cnt = (i == 0) ? 63.0f
                    : (i < 3)  ? 31.0f
                    : (i < 7)  ? 15.0f
                    : (i < 15) ? 7.0f
                    : (i < 31) ? 3.0f
                               : 1.0f;
    m = fmaxf(m, s[i] + cnt * bcv);
  }
  enc[(size_t)blk * NC + c] = fmaxf(m, 0.0f);
}

// ---------------------------------------------------------------------------
// Pack Whh f32 [768][256] -> f16 uint4 laid out for the v6 scan:
//   out[((dir*3 + rs)*32 + j)*256 + c]  = W_dir[rs*256 + c][j*8 .. j*8+8)
// so the scan's fill  w[rs*32+j] = Wd[(rs*32+j)*256 + c]  is fully coalesced.
// ---------------------------------------------------------------------------
__global__ __launch_bounds__(256) void conv_w_pack(
    const float* __restrict__ Wf, const float* __restrict__ Wb,
    uint4* __restrict__ out) {
  int i = blockIdx.x * 256 + threadIdx.x;  // [0, 2*3*32*256)
  if (i >= 2 * 3 * 32 * 256) return;
  const int dir = i / 24576;
  int rem = i - dir * 24576;
  const int rs = rem >> 13;        // gate row-sel [0,3)
  rem &= 8191;
  const int j = rem >> 8;          // k-chunk [0,32)
  const int c = rem & 255;         // channel [0,256)
  const int row = rs * 256 + c;
  const float* __restrict__ W = dir ? Wb : Wf;
  const float4 a = *(const float4*)&W[(size_t)row * NH + j * 8];
  const float4 b = *(const float4*)&W[(size_t)row * NH + j * 8 + 4];
  __half2 p0 = __floats2half2_rn(a.x, a.y);
  __half2 p1 = __floats2half2_rn(a.z, a.w);
  __half2 p2 = __floats2half2_rn(b.x, b.y);
  __half2 p3 = __floats2half2_rn(b.z, b.w);
  uint4 o;
  o.x = *(unsigned int*)&p0; o.y = *(unsigned int*)&p1;
  o.z = *(unsigned int*)&p2; o.w = *(unsigned int*)&p3;
  out[i] = o;
}

// ---------------------------------------------------------------------------
// GRU scan v6. 64 blocks (dir,b) x 256 threads (4 waves, 1 wave/SIMD,
// __launch_bounds__(256,1) -> up to 512 unified regs/thread).
// Thread c owns ALL THREE gate rows of channel c over the FULL K=256:
// 96 uint4 = 384 regs of f16 weights, truly resident (whole block = 393KB
// = Whh_dir in the CU register file). No cross-lane reduction, no
// divergence; h broadcast via 32 uniform ds_read_b128; ONE barrier/step.
// ---------------------------------------------------------------------------
__global__ __launch_bounds__(256, 1) void gru_scan_v6(
    const uint4* __restrict__ Wpk, const float* __restrict__ GI,
    const float* __restrict__ bhh_f, const float* __restrict__ bhh_b,
    float* __restrict__ out) {
  const int dir = blockIdx.x >> 5;
  const int b = blockIdx.x & 31;
  const int c = threadIdx.x;  // channel [0,256)

  __shared__ __align__(16) uint4 hbuf[2][32];  // h packed f16, double-buffered

  // One-time coalesced fill: 96 x global_load_dwordx4, W rows r/z/n of c.
  const uint4* __restrict__ Wd = Wpk + (size_t)dir * 96 * 256;
  uint4 w[96];
#pragma unroll
  for (int j = 0; j < 96; ++j) w[j] = Wd[(size_t)j * 256 + c];

  const float* __restrict__ bhh = dir ? bhh_b : bhh_f;
  const float br = bhh[c], bz = bhh[c + NH], bn = bhh[c + 2 * NH];
  if (threadIdx.x < 32) ((uint4*)hbuf)[threadIdx.x] = uint4{0u, 0u, 0u, 0u};

  const float* __restrict__ gi_base =
      GI + ((size_t)dir * NB * NL + (size_t)b * NL) * G3;
  float gir, giz, gin;
  {
    const float* g = gi_base + (size_t)(dir ? NL - 1 : 0) * G3;
    gir = g[c]; giz = g[c + NH]; gin = g[c + 2 * NH];
  }
  float hreg = 0.0f, hmax = -1e30f;
  __syncthreads();

  for (int st = 0; st < NL; ++st) {
    // Prefetch next step's gi (independent; hides under the dots).
    float girN, gizN, ginN;
    {
      const int stn = (st + 1 < NL) ? st + 1 : st;
      const int t = dir ? (NL - 1 - stn) : stn;
      const float* g = gi_base + (size_t)t * G3;
      girN = g[c]; gizN = g[c + NH]; ginN = g[c + 2 * NH];
    }
    // Full-K dots for rows r,z,n of channel c. 2 accumulators/gate for ILP.
    const uint4* __restrict__ h4 = hbuf[st & 1];
    float ar0 = 0.f, ar1 = 0.f, az0 = 0.f, az1 = 0.f, an0 = 0.f, an1 = 0.f;
#pragma unroll
    for (int j = 0; j < 32; ++j) {
      uint4 hv = h4[j];
      ar0 = fdot2_(w[j].x, hv.x, ar0);       ar1 = fdot2_(w[j].y, hv.y, ar1);
      ar0 = fdot2_(w[j].z, hv.z, ar0);       ar1 = fdot2_(w[j].w, hv.w, ar1);
      az0 = fdot2_(w[32 + j].x, hv.x, az0);  az1 = fdot2_(w[32 + j].y, hv.y, az1);
      az0 = fdot2_(w[32 + j].z, hv.z, az0);  az1 = fdot2_(w[32 + j].w, hv.w, az1);
      an0 = fdot2_(w[64 + j].x, hv.x, an0);  an1 = fdot2_(w[64 + j].y, hv.y, an1);
      an0 = fdot2_(w[64 + j].z, hv.z, an0);  an1 = fdot2_(w[64 + j].w, hv.w, an1);
    }
    // Gates — every thread owns exactly one channel; no reduction needed.
    float r = sigmoidf_(gir + (ar0 + ar1) + br);
    float z = sigmoidf_(giz + (az0 + az1) + bz);
    float n = tanhf(gin + r * ((an0 + an1) + bn));
    hreg = (1.0f - z) * n + z * hreg;
    hmax = fmaxf(hmax, hreg);
    ((unsigned short*)&hbuf[(st + 1) & 1][0])[c] =
        __half_as_ushort(__float2half_rn(hreg));
    __syncthreads();
    gir = girN; giz = gizN; gin = ginN;
  }
  out[(size_t)b * (2 * NH) + (size_t)dir * NH + c] = hmax;
}

// ---------------------------------------------------------------------------
extern "C" void kernel_launch(void* const* d_in, const int* in_sizes, int n_in,
                              void* d_out, int out_size, void* d_ws, size_t ws_size,
                              hipStream_t stream) {
  const int*   tokens = (const int*)d_in[0];
  const float* emb    = (const float*)d_in[1];
  const float* Wc     = (const float*)d_in[2];
  const float* bc     = (const float*)d_in[3];
  const float* Wih_f  = (const float*)d_in[4];
  const float* Whh_f  = (const float*)d_in[5];
  const float* bih_f  = (const float*)d_in[6];
  const float* bhh_f  = (const float*)d_in[7];
  const float* Wih_b  = (const float*)d_in[8];
  const float* Whh_b  = (const float*)d_in[9];
  const float* bih_b  = (const float*)d_in[10];
  const float* bhh_b  = (const float*)d_in[11];
  float* out = (float*)d_out;

  // Workspace: P[V*C] | enc[B*L*C] | GI[2*B*L*3H] | Wpk[2*96*256] uint4
  float* P   = (float*)d_ws;
  float* enc = P + (size_t)NV * NC;
  float* GI  = enc + (size_t)NB * NL * NC;
  uint4* Wpk = (uint4*)(GI + (size_t)2 * NB * NL * G3);

  // 0) Pack Whh -> scan-layout f16.
  conv_w_pack<<<dim3((2 * 3 * 32 * 256 + 255) / 256), dim3(256), 0, stream>>>(
      Whh_f, Whh_b, Wpk);
  // 1) P = emb @ Wc^T   (V x C)
  gemm_bt_k128<<<dim3((NV + 63) / 64, NC / 128), dim3(256), 0, stream>>>(
      emb, Wc, nullptr, P, NV, NC);
  // 2) tree encode -> enc (B*L x C)
  tree_encode<<<dim3(NB * NL), dim3(128), 0, stream>>>(tokens, P, bc, enc);
  // 3) GI f+b in one launch (blockIdx.z = dir)
  gemm_bt_k128_dual<<<dim3(NB * NL / 64, G3 / 128, 2), dim3(256), 0, stream>>>(
      enc, Wih_f, Wih_b, bih_f, bih_b,
      GI, GI + (size_t)NB * NL * G3, NB * NL, G3);
  // 4) GRU scan v6 — truly register-resident W.
  gru_scan_v6<<<dim3(64), dim3(256), 0, stream>>>(
      Wpk, GI, bhh_f, bhh_b, out);
}

// Round 6
// 296.024 us; speedup vs baseline: 1.2879x; 1.2879x over previous
//
#include <hip/hip_runtime.h>
#include <hip/hip_bf16.h>
#include <hip/hip_fp16.h>
#include <math.h>

// Problem constants: B=32, L=128, D=6, T=63, V=50000, E=C=128, H=256
#define NV 50000
#define NC 128
#define NH 256
#define NB 32
#define NL 128
#define NT 63
#define G3 768   // 3*H

typedef _Float16 half2_t __attribute__((ext_vector_type(2)));

__device__ __forceinline__ float sigmoidf_(float x) { return 1.0f / (1.0f + expf(-x)); }

__device__ __forceinline__ float fdot2_(unsigned int a, unsigned int b, float c) {
#if __has_builtin(__builtin_amdgcn_fdot2)
  return __builtin_amdgcn_fdot2(__builtin_bit_cast(half2_t, a),
                                __builtin_bit_cast(half2_t, b), c, false);
#else
  half2_t ah = __builtin_bit_cast(half2_t, a);
  half2_t bh = __builtin_bit_cast(half2_t, b);
  return fmaf((float)ah[0], (float)bh[0], fmaf((float)ah[1], (float)bh[1], c));
#endif
}

// quad_perm [1,0,3,2]: swap lane pairs (xor 1) — VALU only, no LDS pipe.
__device__ __forceinline__ float dpp_xor1_add(float v) {
  int x = __builtin_amdgcn_update_dpp(0, __builtin_bit_cast(int, v),
                                      0xB1, 0xF, 0xF, true);
  return v + __builtin_bit_cast(float, x);
}

// ---------------------------------------------------------------------------
// C[m][n] = sum_k A[m][k]*B[n][k] (+bias), K=128. B staged in two k-halves.
// ---------------------------------------------------------------------------
__global__ __launch_bounds__(256) void gemm_bt_k128(
    const float* __restrict__ A, const float* __restrict__ Bm,
    const float* __restrict__ bias, float* __restrict__ Cm,
    int M, int N) {
  __shared__ __align__(16) float As[64 * 129];
  __shared__ __align__(16) float BsT[64 * 132];  // [kk][n], one k-half
  const int m0 = blockIdx.x * 64;
  const int n0 = blockIdx.y * 128;
  const int tid = threadIdx.x;

#pragma unroll
  for (int i = 0; i < 32; ++i) {
    int e = tid + i * 256;
    int r = e >> 7, k = e & 127;
    int m = m0 + r;
    As[r * 129 + k] = (m < M) ? A[(size_t)m * 128 + k] : 0.0f;
  }

  const int tn = tid & 15;
  const int tm = tid >> 4;
  const int ml = tm * 4, nl = tn * 8;

  float acc[4][8];
#pragma unroll
  for (int i = 0; i < 4; ++i)
#pragma unroll
    for (int j = 0; j < 8; ++j) acc[i][j] = 0.0f;

#pragma unroll
  for (int h = 0; h < 2; ++h) {
    if (h) __syncthreads();
#pragma unroll
    for (int i = 0; i < 32; ++i) {
      int e = tid + i * 256;
      int n = e >> 6, kk = e & 63;
      BsT[kk * 132 + n] = Bm[(size_t)(n0 + n) * 128 + h * 64 + kk];
    }
    __syncthreads();
#pragma unroll 4
    for (int kk = 0; kk < 64; ++kk) {
      const int k = h * 64 + kk;
      float a0 = As[(ml + 0) * 129 + k];
      float a1 = As[(ml + 1) * 129 + k];
      float a2 = As[(ml + 2) * 129 + k];
      float a3 = As[(ml + 3) * 129 + k];
      float4 b0 = *(const float4*)&BsT[kk * 132 + nl];
      float4 b1 = *(const float4*)&BsT[kk * 132 + nl + 4];
      const float bv[8] = {b0.x, b0.y, b0.z, b0.w, b1.x, b1.y, b1.z, b1.w};
#pragma unroll
      for (int j = 0; j < 8; ++j) {
        acc[0][j] = fmaf(a0, bv[j], acc[0][j]);
        acc[1][j] = fmaf(a1, bv[j], acc[1][j]);
        acc[2][j] = fmaf(a2, bv[j], acc[2][j]);
        acc[3][j] = fmaf(a3, bv[j], acc[3][j]);
      }
    }
  }

  float bv[8];
#pragma unroll
  for (int j = 0; j < 8; ++j) bv[j] = bias ? bias[n0 + nl + j] : 0.0f;

#pragma unroll
  for (int i = 0; i < 4; ++i) {
    int m = m0 + ml + i;
    if (m < M) {
      float* crow = &Cm[(size_t)m * N + n0 + nl];
#pragma unroll
      for (int j = 0; j < 8; ++j) crow[j] = acc[i][j] + bv[j];
    }
  }
}

// ---------------------------------------------------------------------------
// Dual GEMM: blockIdx.z picks f/b weight+bias+output.
// ---------------------------------------------------------------------------
__global__ __launch_bounds__(256) void gemm_bt_k128_dual(
    const float* __restrict__ A,
    const float* __restrict__ B0, const float* __restrict__ B1,
    const float* __restrict__ bias0, const float* __restrict__ bias1,
    float* __restrict__ C0, float* __restrict__ C1, int M, int N) {
  const float* __restrict__ Bm = blockIdx.z ? B1 : B0;
  const float* __restrict__ bias = blockIdx.z ? bias1 : bias0;
  float* __restrict__ Cm = blockIdx.z ? C1 : C0;

  __shared__ __align__(16) float As[64 * 129];
  __shared__ __align__(16) float BsT[64 * 132];
  const int m0 = blockIdx.x * 64;
  const int n0 = blockIdx.y * 128;
  const int tid = threadIdx.x;

#pragma unroll
  for (int i = 0; i < 32; ++i) {
    int e = tid + i * 256;
    int r = e >> 7, k = e & 127;
    int m = m0 + r;
    As[r * 129 + k] = (m < M) ? A[(size_t)m * 128 + k] : 0.0f;
  }

  const int tn = tid & 15;
  const int tm = tid >> 4;
  const int ml = tm * 4, nl = tn * 8;

  float acc[4][8];
#pragma unroll
  for (int i = 0; i < 4; ++i)
#pragma unroll
    for (int j = 0; j < 8; ++j) acc[i][j] = 0.0f;

#pragma unroll
  for (int h = 0; h < 2; ++h) {
    if (h) __syncthreads();
#pragma unroll
    for (int i = 0; i < 32; ++i) {
      int e = tid + i * 256;
      int n = e >> 6, kk = e & 63;
      BsT[kk * 132 + n] = Bm[(size_t)(n0 + n) * 128 + h * 64 + kk];
    }
    __syncthreads();
#pragma unroll 4
    for (int kk = 0; kk < 64; ++kk) {
      const int k = h * 64 + kk;
      float a0 = As[(ml + 0) * 129 + k];
      float a1 = As[(ml + 1) * 129 + k];
      float a2 = As[(ml + 2) * 129 + k];
      float a3 = As[(ml + 3) * 129 + k];
      float4 b0 = *(const float4*)&BsT[kk * 132 + nl];
      float4 b1 = *(const float4*)&BsT[kk * 132 + nl + 4];
      const float bv[8] = {b0.x, b0.y, b0.z, b0.w, b1.x, b1.y, b1.z, b1.w};
#pragma unroll
      for (int j = 0; j < 8; ++j) {
        acc[0][j] = fmaf(a0, bv[j], acc[0][j]);
        acc[1][j] = fmaf(a1, bv[j], acc[1][j]);
        acc[2][j] = fmaf(a2, bv[j], acc[2][j]);
        acc[3][j] = fmaf(a3, bv[j], acc[3][j]);
      }
    }
  }

  float bv[8];
#pragma unroll
  for (int j = 0; j < 8; ++j) bv[j] = bias[n0 + nl + j];

#pragma unroll
  for (int i = 0; i < 4; ++i) {
    int m = m0 + ml + i;
    if (m < M) {
      float* crow = &Cm[(size_t)m * N + n0 + nl];
#pragma unroll
      for (int j = 0; j < 8; ++j) crow[j] = acc[i][j] + bv[j];
    }
  }
}

// ---------------------------------------------------------------------------
// Tree encode: per (b,l), heap-sum P[tok], + cnt*bc, max, relu.
// ---------------------------------------------------------------------------
__global__ __launch_bounds__(128) void tree_encode(
    const int* __restrict__ tokens, const float* __restrict__ P,
    const float* __restrict__ bc, float* __restrict__ enc) {
  __shared__ int toks[NT];
  const int blk = blockIdx.x;
  const int c = threadIdx.x;
  if (c < NT) toks[c] = tokens[(size_t)blk * NT + c];
  __syncthreads();

  float s[NT];
#pragma unroll
  for (int i = 0; i < NT; ++i) s[i] = P[(size_t)toks[i] * NC + c];
#pragma unroll
  for (int i = 30; i >= 0; --i) s[i] += s[2 * i + 1] + s[2 * i + 2];

  const float bcv = bc[c];
  float m = -1e30f;
#pragma unroll
  for (int i = 0; i < NT; ++i) {
    const float cnt = (i == 0) ? 63.0f
                    : (i < 3)  ? 31.0f
                    : (i < 7)  ? 15.0f
                    : (i < 15) ? 7.0f
                    : (i < 31) ? 3.0f
                               : 1.0f;
    m = fmaxf(m, s[i] + cnt * bcv);
  }
  enc[(size_t)blk * NC + c] = fmaxf(m, 0.0f);
}

// ---------------------------------------------------------------------------
// Pack Whh f32 [768][256] -> f16 uint4 for the v7 scan:
//   i = ((dir*48 + q)*512 + tid),  q = g*16 + j,  tid = c*2 + kh
//   holds W_dir[g*256 + c][kh*128 + j*8 .. +8)
// Scan fill  w[q] = Wd[q*512 + tid]  is fully coalesced.
// ---------------------------------------------------------------------------
__global__ __launch_bounds__(256) void conv_w_pack(
    const float* __restrict__ Wf, const float* __restrict__ Wb,
    uint4* __restrict__ out) {
  int i = blockIdx.x * 256 + threadIdx.x;  // [0, 2*48*512)
  if (i >= 2 * 48 * 512) return;
  const int dir = i / 24576;
  int rem = i - dir * 24576;
  const int q = rem >> 9;          // [0,48)
  const int tid = rem & 511;
  const int g = q >> 4;            // gate [0,3)
  const int j = q & 15;            // k-chunk [0,16)
  const int c = tid >> 1;
  const int kh = tid & 1;
  const int row = g * 256 + c;
  const int k0 = kh * 128 + j * 8;
  const float* __restrict__ W = dir ? Wb : Wf;
  const float4 a = *(const float4*)&W[(size_t)row * NH + k0];
  const float4 b = *(const float4*)&W[(size_t)row * NH + k0 + 4];
  __half2 p0 = __floats2half2_rn(a.x, a.y);
  __half2 p1 = __floats2half2_rn(a.z, a.w);
  __half2 p2 = __floats2half2_rn(b.x, b.y);
  __half2 p3 = __floats2half2_rn(b.z, b.w);
  uint4 o;
  o.x = *(unsigned int*)&p0; o.y = *(unsigned int*)&p1;
  o.z = *(unsigned int*)&p2; o.w = *(unsigned int*)&p3;
  out[i] = o;
}

// ---------------------------------------------------------------------------
// GRU scan v7. 64 blocks (dir,b) x 512 threads (8 waves, 2/SIMD, cap 256
// VGPR). Thread (c,kh) holds rows r/z/n of channel c over half of K:
// 48 uint4 = 192 VGPRs, FORCED resident via empty-asm pins (blocks the
// compiler's load-rematerialization, which wrecked v3-v6). Pair partials
// combined with one DPP quad_perm add per gate. h double-buffered at
// 17-uint4 stride (disjoint banks for the two kh groups). One barrier/step.
// ---------------------------------------------------------------------------
__global__ __launch_bounds__(512, 2) void gru_scan_v7(
    const uint4* __restrict__ Wpk, const float* __restrict__ GI,
    const float* __restrict__ bhh_f, const float* __restrict__ bhh_b,
    float* __restrict__ out) {
  const int dir = blockIdx.x >> 5;
  const int b = blockIdx.x & 31;
  const int tid = threadIdx.x;
  const int c = tid >> 1;   // channel [0,256)
  const int kh = tid & 1;   // k-half

  // h packed f16, double-buffered; halves at uint4 stride 17 -> the two
  // kh address groups land on disjoint banks.
  __shared__ __align__(16) uint4 hbuf[2][34];

  // One-time coalesced fill, then PIN each weight register: the empty asm
  // "defines" the values, making load-sinking/remat illegal.
  const uint4* __restrict__ Wd = Wpk + (size_t)dir * 48 * 512;
  uint4 w[48];
#pragma unroll
  for (int q = 0; q < 48; ++q) w[q] = Wd[(size_t)q * 512 + tid];
#pragma unroll
  for (int q = 0; q < 48; ++q)
    asm volatile("" : "+v"(w[q].x), "+v"(w[q].y), "+v"(w[q].z), "+v"(w[q].w));

  const float* __restrict__ bhh = dir ? bhh_b : bhh_f;
  const float br = bhh[c], bz = bhh[c + NH], bn = bhh[c + 2 * NH];
  if (tid < 136) ((unsigned int*)hbuf)[tid] = 0u;  // zero hbuf[0]

  const float* __restrict__ gi_base =
      GI + ((size_t)dir * NB * NL + (size_t)b * NL) * G3;
  float gir, giz, gin;
  {
    const float* g = gi_base + (size_t)(dir ? NL - 1 : 0) * G3;
    gir = g[c]; giz = g[c + NH]; gin = g[c + 2 * NH];
  }
  float hreg = 0.0f, hmax = -1e30f;
  const int hidx = c + ((c >> 7) << 3);  // ushort index with 17-stride halves
  __syncthreads();

  for (int st = 0; st < NL; ++st) {
    // Prefetch next step's gi (independent of h; hides under the dots).
    float girN, gizN, ginN;
    {
      const int stn = (st + 1 < NL) ? st + 1 : st;
      const int t = dir ? (NL - 1 - stn) : stn;
      const float* g = gi_base + (size_t)t * G3;
      girN = g[c]; gizN = g[c + NH]; ginN = g[c + 2 * NH];
    }
    // Half-K dots for rows r,z,n of channel c.
    const uint4* __restrict__ hp = hbuf[st & 1] + kh * 17;
    float ar = 0.f, az = 0.f, an = 0.f;
#pragma unroll
    for (int j = 0; j < 16; ++j) {
      uint4 hv = hp[j];
      ar = fdot2_(w[j].x, hv.x, ar);       ar = fdot2_(w[j].y, hv.y, ar);
      ar = fdot2_(w[j].z, hv.z, ar);       ar = fdot2_(w[j].w, hv.w, ar);
      az = fdot2_(w[16 + j].x, hv.x, az);  az = fdot2_(w[16 + j].y, hv.y, az);
      az = fdot2_(w[16 + j].z, hv.z, az);  az = fdot2_(w[16 + j].w, hv.w, az);
      an = fdot2_(w[32 + j].x, hv.x, an);  an = fdot2_(w[32 + j].y, hv.y, an);
      an = fdot2_(w[32 + j].z, hv.z, an);  an = fdot2_(w[32 + j].w, hv.w, an);
    }
    // Combine the two k-halves within the lane pair (VALU-only DPP).
    ar = dpp_xor1_add(ar);
    az = dpp_xor1_add(az);
    an = dpp_xor1_add(an);
    // Gates, computed redundantly in both lanes (no divergence).
    float r = sigmoidf_(gir + ar + br);
    float z = sigmoidf_(giz + az + bz);
    float n = tanhf(gin + r * (an + bn));
    hreg = (1.0f - z) * n + z * hreg;
    hmax = fmaxf(hmax, hreg);
    if (kh == 0) {
      ((unsigned short*)&hbuf[(st + 1) & 1][0])[hidx] =
          __half_as_ushort(__float2half_rn(hreg));
    }
    __syncthreads();
    gir = girN; giz = gizN; gin = ginN;
  }
  if (kh == 0) out[(size_t)b * (2 * NH) + (size_t)dir * NH + c] = hmax;
}

// ---------------------------------------------------------------------------
extern "C" void kernel_launch(void* const* d_in, const int* in_sizes, int n_in,
                              void* d_out, int out_size, void* d_ws, size_t ws_size,
                              hipStream_t stream) {
  const int*   tokens = (const int*)d_in[0];
  const float* emb    = (const float*)d_in[1];
  const float* Wc     = (const float*)d_in[2];
  const float* bc     = (const float*)d_in[3];
  const float* Wih_f  = (const float*)d_in[4];
  const float* Whh_f  = (const float*)d_in[5];
  const float* bih_f  = (const float*)d_in[6];
  const float* bhh_f  = (const float*)d_in[7];
  const float* Wih_b  = (const float*)d_in[8];
  const float* Whh_b  = (const float*)d_in[9];
  const float* bih_b  = (const float*)d_in[10];
  const float* bhh_b  = (const float*)d_in[11];
  float* out = (float*)d_out;

  // Workspace: P[V*C] | enc[B*L*C] | GI[2*B*L*3H] | Wpk[2*48*512] uint4
  float* P   = (float*)d_ws;
  float* enc = P + (size_t)NV * NC;
  float* GI  = enc + (size_t)NB * NL * NC;
  uint4* Wpk = (uint4*)(GI + (size_t)2 * NB * NL * G3);

  // 0) Pack Whh -> scan-layout f16.
  conv_w_pack<<<dim3((2 * 48 * 512 + 255) / 256), dim3(256), 0, stream>>>(
      Whh_f, Whh_b, Wpk);
  // 1) P = emb @ Wc^T   (V x C)
  gemm_bt_k128<<<dim3((NV + 63) / 64, NC / 128), dim3(256), 0, stream>>>(
      emb, Wc, nullptr, P, NV, NC);
  // 2) tree encode -> enc (B*L x C)
  tree_encode<<<dim3(NB * NL), dim3(128), 0, stream>>>(tokens, P, bc, enc);
  // 3) GI f+b in one launch (blockIdx.z = dir)
  gemm_bt_k128_dual<<<dim3(NB * NL / 64, G3 / 128, 2), dim3(256), 0, stream>>>(
      enc, Wih_f, Wih_b, bih_f, bih_b,
      GI, GI + (size_t)NB * NL * G3, NB * NL, G3);
  // 4) GRU scan v7 — asm-pinned register-resident W.
  gru_scan_v7<<<dim3(64), dim3(512), 0, stream>>>(
      Wpk, GI, bhh_f, bhh_b, out);
}